// Round 3
// baseline (2544.101 us; speedup 1.0000x reference)
//
#include <hip/hip_runtime.h>
#include <hip/hip_bf16.h>
#include <stdint.h>

#define TOKENS 2048
#define HIDDEN 2048
#define INTER  1408
#define NEXP   8
#define TOPK   2
#define NPAIR  (TOKENS*TOPK)   // 4096

#define SK 72   // padded LDS row stride (bf16 elems): 144 B -> uniform bank spread

typedef __attribute__((ext_vector_type(8))) short bf16x8;
typedef __attribute__((ext_vector_type(4))) float f32x4;

static __device__ __forceinline__ unsigned short f2b(float f) {
    union { float f; uint32_t u; } v; v.f = f;
    uint32_t r = (v.u + 0x7FFFu + ((v.u >> 16) & 1u)) >> 16;   // RNE
    return (unsigned short)r;
}

// ---------------- routing: pack (token, weight) per expert ----------------
__global__ void route_k(const int* __restrict__ idx, const float* __restrict__ w,
                        int* __restrict__ off, int* __restrict__ tok,
                        float* __restrict__ wgt) {
    __shared__ int cnt[NEXP];
    __shared__ int cur[NEXP];
    int tid = threadIdx.x;
    if (tid < NEXP) cnt[tid] = 0;
    __syncthreads();
    for (int i = tid; i < NPAIR; i += 256) atomicAdd(&cnt[idx[i]], 1);
    __syncthreads();
    if (tid == 0) {
        int s = 0;
        for (int e = 0; e < NEXP; ++e) { off[e] = s; cur[e] = s; s += cnt[e]; }
        off[NEXP] = s;
    }
    __syncthreads();
    for (int i = tid; i < NPAIR; i += 256) {
        int e = idx[i];
        int p = atomicAdd(&cur[e], 1);
        tok[p] = i >> 1;
        wgt[p] = w[i];
    }
}

// ---------------- fp32 -> bf16 bulk convert ----------------
__global__ void conv_k(const float* __restrict__ x, unsigned short* __restrict__ xb, int n) {
    int i = (blockIdx.x * blockDim.x + threadIdx.x) * 4;
    if (i < n) {
        float4 v = *(const float4*)(x + i);
        ushort4 o;
        o.x = f2b(v.x); o.y = f2b(v.y); o.z = f2b(v.z); o.w = f2b(v.w);
        *(ushort4*)(xb + i) = o;
    }
}

// =================== GEMM1: gate+up fused, SwiGLU -> H (bf16) ===================
// tile 128(M pairs) x 64(N inter), BK=64, K=2048 (32 steps)
// staging: plain dwordx4 -> regs -> ds_write (SK=72 pad), reg-level k+1 prefetch
__global__ __launch_bounds__(256, 3) void gemm1_k(
    const unsigned short* __restrict__ Xb,
    const unsigned short* __restrict__ Wgb, const unsigned short* __restrict__ Wub,
    const int* __restrict__ off, const int* __restrict__ tok,
    unsigned short* __restrict__ H) {

    const int e    = blockIdx.z;
    const int o0   = off[e];
    const int cnt  = off[e + 1] - o0;
    const int row0 = blockIdx.x * 128;
    if (row0 >= cnt) return;
    const int col0 = blockIdx.y * 64;

    __shared__ __align__(16) unsigned short sA[128 * SK];
    __shared__ __align__(16) unsigned short sG[64 * SK];
    __shared__ __align__(16) unsigned short sU[64 * SK];
    __shared__ int stok[128];

    const int tid = threadIdx.x;
    if (tid < 128) {
        int r = row0 + tid;
        stok[tid] = tok[o0 + (r < cnt ? r : cnt - 1)];
    }
    __syncthreads();

    // staging decomposition: 16B segments; A: 128x8 segs (4/thr), G/U: 64x8 segs (2/thr)
    int rA[4], cA[4];
    const unsigned short* gA[4];
    #pragma unroll
    for (int j = 0; j < 4; ++j) {
        int si = tid + 256 * j;
        rA[j] = si >> 3; cA[j] = (si & 7) * 8;
        gA[j] = Xb + (size_t)stok[rA[j]] * HIDDEN + cA[j];
    }
    int rB[2], cB[2];
    const unsigned short* gG[2]; const unsigned short* gU[2];
    #pragma unroll
    for (int j = 0; j < 2; ++j) {
        int si = tid + 256 * j;
        rB[j] = si >> 3; cB[j] = (si & 7) * 8;
        gG[j] = Wgb + ((size_t)e * INTER + col0 + rB[j]) * HIDDEN + cB[j];
        gU[j] = Wub + ((size_t)e * INTER + col0 + rB[j]) * HIDDEN + cB[j];
    }

    const int wave = tid >> 6, lane = tid & 63;
    const int wr = wave >> 1, wc = wave & 1;           // 2x2 wave grid
    const int wm = wr * 64, wn = wc * 32;
    const int lm = lane & 15, quad = lane >> 4;

    f32x4 accg[4][2], accu[4][2];
    #pragma unroll
    for (int i = 0; i < 4; ++i)
        #pragma unroll
        for (int j = 0; j < 2; ++j) {
            accg[i][j] = (f32x4){0.f, 0.f, 0.f, 0.f};
            accu[i][j] = (f32x4){0.f, 0.f, 0.f, 0.f};
        }

    int4 ra[4], rg[2], ru[2];
    #pragma unroll
    for (int j = 0; j < 4; ++j) ra[j] = *(const int4*)(gA[j]);
    #pragma unroll
    for (int j = 0; j < 2; ++j) { rg[j] = *(const int4*)(gG[j]); ru[j] = *(const int4*)(gU[j]); }

    for (int ks = 0; ks < HIDDEN / 64; ++ks) {
        #pragma unroll
        for (int j = 0; j < 4; ++j) *(int4*)&sA[rA[j] * SK + cA[j]] = ra[j];
        #pragma unroll
        for (int j = 0; j < 2; ++j) {
            *(int4*)&sG[rB[j] * SK + cB[j]] = rg[j];
            *(int4*)&sU[rB[j] * SK + cB[j]] = ru[j];
        }
        __syncthreads();

        if (ks + 1 < HIDDEN / 64) {      // prefetch next K-slice; overlaps MFMA below
            int k1 = (ks + 1) * 64;
            #pragma unroll
            for (int j = 0; j < 4; ++j) ra[j] = *(const int4*)(gA[j] + k1);
            #pragma unroll
            for (int j = 0; j < 2; ++j) { rg[j] = *(const int4*)(gG[j] + k1); ru[j] = *(const int4*)(gU[j] + k1); }
        }

        #pragma unroll
        for (int kk = 0; kk < 64; kk += 32) {
            bf16x8 af[4], gf[2], uf[2];
            #pragma unroll
            for (int mi = 0; mi < 4; ++mi)
                af[mi] = *(const bf16x8*)&sA[(wm + mi * 16 + lm) * SK + kk + quad * 8];
            #pragma unroll
            for (int ni = 0; ni < 2; ++ni) {
                gf[ni] = *(const bf16x8*)&sG[(wn + ni * 16 + lm) * SK + kk + quad * 8];
                uf[ni] = *(const bf16x8*)&sU[(wn + ni * 16 + lm) * SK + kk + quad * 8];
            }
            #pragma unroll
            for (int mi = 0; mi < 4; ++mi)
                #pragma unroll
                for (int ni = 0; ni < 2; ++ni) {
                    accg[mi][ni] = __builtin_amdgcn_mfma_f32_16x16x32_bf16(af[mi], gf[ni], accg[mi][ni], 0, 0, 0);
                    accu[mi][ni] = __builtin_amdgcn_mfma_f32_16x16x32_bf16(af[mi], uf[ni], accu[mi][ni], 0, 0, 0);
                }
        }
        __syncthreads();
    }

    #pragma unroll
    for (int mi = 0; mi < 4; ++mi) {
        #pragma unroll
        for (int reg = 0; reg < 4; ++reg) {
            int lr = wm + mi * 16 + quad * 4 + reg;    // C/D: col=lane&15, row=quad*4+reg
            int r  = row0 + lr;
            if (r < cnt) {
                size_t hrow = (size_t)(o0 + r) * INTER;
                #pragma unroll
                for (int ni = 0; ni < 2; ++ni) {
                    float g = accg[mi][ni][reg];
                    float u = accu[mi][ni][reg];
                    float h = g / (1.f + __expf(-g)) * u;
                    H[hrow + col0 + wn + ni * 16 + lm] = f2b(h);
                }
            }
        }
    }
}

// =================== GEMM2: down proj, weighted atomic combine ===================
// tile 128(M pairs) x 128(N hidden), BK=64, K=1408 (22 steps)
__global__ __launch_bounds__(256, 3) void gemm2_k(
    const unsigned short* __restrict__ H,
    const unsigned short* __restrict__ Wdb,
    const int* __restrict__ off, const int* __restrict__ tok,
    const float* __restrict__ wgt,
    float* __restrict__ out) {

    const int e    = blockIdx.z;
    const int o0   = off[e];
    const int cnt  = off[e + 1] - o0;
    const int row0 = blockIdx.x * 128;
    if (row0 >= cnt) return;
    const int col0 = blockIdx.y * 128;

    __shared__ __align__(16) unsigned short sA[128 * SK];
    __shared__ __align__(16) unsigned short sB[128 * SK];
    __shared__ int   stok[128];
    __shared__ float swgt[128];

    const int tid = threadIdx.x;
    if (tid < 128) {
        int r  = row0 + tid;
        int rr = (r < cnt ? r : cnt - 1);
        stok[tid] = tok[o0 + rr];
        swgt[tid] = wgt[o0 + rr];
    }
    __syncthreads();

    int rA[4], cA[4], rB[4], cB[4];
    const unsigned short* gA[4]; const unsigned short* gB[4];
    #pragma unroll
    for (int j = 0; j < 4; ++j) {
        int si = tid + 256 * j;
        rA[j] = si >> 3; cA[j] = (si & 7) * 8;
        int gr = row0 + rA[j]; if (gr >= cnt) gr = cnt - 1;
        gA[j] = H + (size_t)(o0 + gr) * INTER + cA[j];
        rB[j] = rA[j]; cB[j] = cA[j];
        gB[j] = Wdb + ((size_t)e * HIDDEN + col0 + rB[j]) * INTER + cB[j];
    }

    const int wave = tid >> 6, lane = tid & 63;
    const int wr = wave >> 1, wc = wave & 1;
    const int wm = wr * 64, wn = wc * 64;
    const int lm = lane & 15, quad = lane >> 4;

    f32x4 acc[4][4];
    #pragma unroll
    for (int i = 0; i < 4; ++i)
        #pragma unroll
        for (int j = 0; j < 4; ++j) acc[i][j] = (f32x4){0.f, 0.f, 0.f, 0.f};

    int4 ra[4], rb[4];
    #pragma unroll
    for (int j = 0; j < 4; ++j) { ra[j] = *(const int4*)(gA[j]); rb[j] = *(const int4*)(gB[j]); }

    for (int ks = 0; ks < INTER / 64; ++ks) {
        #pragma unroll
        for (int j = 0; j < 4; ++j) {
            *(int4*)&sA[rA[j] * SK + cA[j]] = ra[j];
            *(int4*)&sB[rB[j] * SK + cB[j]] = rb[j];
        }
        __syncthreads();

        if (ks + 1 < INTER / 64) {
            int k1 = (ks + 1) * 64;
            #pragma unroll
            for (int j = 0; j < 4; ++j) { ra[j] = *(const int4*)(gA[j] + k1); rb[j] = *(const int4*)(gB[j] + k1); }
        }

        #pragma unroll
        for (int kk = 0; kk < 64; kk += 32) {
            bf16x8 af[4], bf[4];
            #pragma unroll
            for (int mi = 0; mi < 4; ++mi)
                af[mi] = *(const bf16x8*)&sA[(wm + mi * 16 + lm) * SK + kk + quad * 8];
            #pragma unroll
            for (int ni = 0; ni < 4; ++ni)
                bf[ni] = *(const bf16x8*)&sB[(wn + ni * 16 + lm) * SK + kk + quad * 8];
            #pragma unroll
            for (int mi = 0; mi < 4; ++mi)
                #pragma unroll
                for (int ni = 0; ni < 4; ++ni)
                    acc[mi][ni] = __builtin_amdgcn_mfma_f32_16x16x32_bf16(af[mi], bf[ni], acc[mi][ni], 0, 0, 0);
        }
        __syncthreads();
    }

    #pragma unroll
    for (int mi = 0; mi < 4; ++mi) {
        #pragma unroll
        for (int reg = 0; reg < 4; ++reg) {
            int lr = wm + mi * 16 + quad * 4 + reg;
            int r  = row0 + lr;
            if (r < cnt) {
                int   t = stok[lr];
                float w = swgt[lr];
                #pragma unroll
                for (int ni = 0; ni < 4; ++ni)
                    atomicAdd(&out[(size_t)t * HIDDEN + col0 + wn + ni * 16 + lm],
                              w * acc[mi][ni][reg]);
            }
        }
    }
}

extern "C" void kernel_launch(void* const* d_in, const int* in_sizes, int n_in,
                              void* d_out, int out_size, void* d_ws, size_t ws_size,
                              hipStream_t stream) {
    const float* X   = (const float*)d_in[0];
    const int*   idx = (const int*)d_in[1];
    const float* tw  = (const float*)d_in[2];
    const float* Wg  = (const float*)d_in[3];
    const float* Wu  = (const float*)d_in[4];
    const float* Wd  = (const float*)d_in[5];
    float* out = (float*)d_out;

    char* ws = (char*)d_ws;
    const size_t OFF_TOK = 64;
    const size_t OFF_WGT = 64 + (size_t)NPAIR * 4;
    const size_t OFF_XB  = 65536;
    const size_t OFF_H   = OFF_XB + (size_t)TOKENS * HIDDEN * 2;           // 8 MB Xb
    const size_t WELEMS  = (size_t)NEXP * INTER * HIDDEN;                  // 23.07M
    const size_t OFF_WG  = OFF_H + (size_t)NPAIR * INTER * 2;              // 11.5 MB H
    const size_t OFF_WU  = OFF_WG + WELEMS * 2;
    const size_t OFF_WD  = OFF_WU + WELEMS * 2;

    int*            off = (int*)ws;
    int*            tok = (int*)(ws + OFF_TOK);
    float*          wgt = (float*)(ws + OFF_WGT);
    unsigned short* Xb  = (unsigned short*)(ws + OFF_XB);
    unsigned short* H   = (unsigned short*)(ws + OFF_H);
    unsigned short* Wgb = (unsigned short*)(ws + OFF_WG);
    unsigned short* Wub = (unsigned short*)(ws + OFF_WU);
    unsigned short* Wdb = (unsigned short*)(ws + OFF_WD);

    hipMemsetAsync(d_out, 0, (size_t)out_size * sizeof(float), stream);

    route_k<<<1, 256, 0, stream>>>(idx, tw, off, tok, wgt);
    conv_k<<<(TOKENS * HIDDEN / 4 + 255) / 256, 256, 0, stream>>>(X, Xb, TOKENS * HIDDEN);

    const int wn4 = (int)(WELEMS / 4);
    conv_k<<<(wn4 + 255) / 256, 256, 0, stream>>>(Wg, Wgb, (int)WELEMS);
    conv_k<<<(wn4 + 255) / 256, 256, 0, stream>>>(Wu, Wub, (int)WELEMS);
    conv_k<<<(wn4 + 255) / 256, 256, 0, stream>>>(Wd, Wdb, (int)WELEMS);

    gemm1_k<<<dim3(NPAIR / 128, INTER / 64, NEXP), 256, 0, stream>>>(Xb, Wgb, Wub, off, tok, H);
    gemm2_k<<<dim3(NPAIR / 128, HIDDEN / 128, NEXP), 256, 0, stream>>>(H, Wdb, off, tok, wgt, out);
}

// Round 4
// 1104.892 us; speedup vs baseline: 2.3026x; 2.3026x over previous
//
#include <hip/hip_runtime.h>
#include <hip/hip_bf16.h>
#include <stdint.h>

#define TOKENS 2048
#define HIDDEN 2048
#define INTER  1408
#define NEXP   8
#define NPAIR  4096

typedef __attribute__((ext_vector_type(8))) short bf16x8;
typedef __attribute__((ext_vector_type(4))) float f32x4;

static __device__ __forceinline__ unsigned short f2b(float f) {
    union { float f; uint32_t u; } v; v.f = f;
    uint32_t r = (v.u + 0x7FFFu + ((v.u >> 16) & 1u)) >> 16;   // RNE
    return (unsigned short)r;
}

// async global->LDS, 16B/lane. global addr per-lane (gather OK); LDS dest is
// wave-uniform base, HW scatters lane i to base + i*16.
static __device__ __forceinline__ void gll16(const unsigned short* g, unsigned short* l) {
    __builtin_amdgcn_global_load_lds(
        (const __attribute__((address_space(1))) void*)g,
        (__attribute__((address_space(3))) void*)l,
        16, 0, 0);
}

// ---------------- routing: pack (token, weight) per expert ----------------
__global__ void route_k(const int* __restrict__ idx, const float* __restrict__ w,
                        int* __restrict__ off, int* __restrict__ tok,
                        float* __restrict__ wgt) {
    __shared__ int cnt[NEXP];
    __shared__ int cur[NEXP];
    int tid = threadIdx.x;
    if (tid < NEXP) cnt[tid] = 0;
    __syncthreads();
    for (int i = tid; i < NPAIR; i += 256) atomicAdd(&cnt[idx[i]], 1);
    __syncthreads();
    if (tid == 0) {
        int s = 0;
        for (int e = 0; e < NEXP; ++e) { off[e] = s; cur[e] = s; s += cnt[e]; }
        off[NEXP] = s;
    }
    __syncthreads();
    for (int i = tid; i < NPAIR; i += 256) {
        int e = idx[i];
        int p = atomicAdd(&cur[e], 1);
        tok[p] = i >> 1;
        wgt[p] = w[i];
    }
}

// ---------------- fp32 -> bf16 bulk convert ----------------
__global__ void conv_k(const float* __restrict__ x, unsigned short* __restrict__ xb, int n) {
    int i = (blockIdx.x * blockDim.x + threadIdx.x) * 4;
    if (i < n) {
        float4 v = *(const float4*)(x + i);
        ushort4 o;
        o.x = f2b(v.x); o.y = f2b(v.y); o.z = f2b(v.z); o.w = f2b(v.w);
        *(ushort4*)(xb + i) = o;
    }
}

// =================== GEMM1: gate+up fused, SwiGLU -> H (bf16) ===================
// tile 128(M) x 64(N), BK=64, K=2048 (32 steps). Double-buffered async
// global_load_lds; XOR-swizzled LDS segments (no padding); 1 barrier/step.
__global__ __launch_bounds__(256, 2) void gemm1_k(
    const unsigned short* __restrict__ Xb,
    const unsigned short* __restrict__ Wgb, const unsigned short* __restrict__ Wub,
    const int* __restrict__ off, const int* __restrict__ tok,
    unsigned short* __restrict__ H) {

    const int e    = blockIdx.z;
    const int o0   = off[e];
    const int cnt  = off[e + 1] - o0;
    const int row0 = blockIdx.x * 128;
    if (row0 >= cnt) return;
    const int col0 = blockIdx.y * 64;

    __shared__ __align__(16) unsigned short sA[2][128 * 64];
    __shared__ __align__(16) unsigned short sG[2][64 * 64];
    __shared__ __align__(16) unsigned short sU[2][64 * 64];
    __shared__ int stok[128];

    const int tid = threadIdx.x;
    if (tid < 128) {
        int r = row0 + tid;
        stok[tid] = tok[o0 + (r < cnt ? r : cnt - 1)];
    }
    __syncthreads();

    const int wave = tid >> 6, lane = tid & 63;
    const int r8  = lane >> 3;            // row within 8-row DMA chunk
    const int spn = lane & 7;             // physical 16B segment this lane fills
    const int sgm = spn ^ r8;             // swizzle: load logical seg spn^ (row&7)

    // per-lane global sources (pointer-only; no data regs -> no spills)
    const unsigned short* gA[4];
    unsigned short* lA[4];
    #pragma unroll
    for (int j = 0; j < 4; ++j) {
        int row = wave * 32 + j * 8 + r8;
        gA[j] = Xb + (size_t)stok[row] * HIDDEN + sgm * 8;
        lA[j] = &sA[0][(wave * 32 + j * 8) * 64];
    }
    const unsigned short* gG[2]; const unsigned short* gU[2];
    unsigned short* lG[2]; unsigned short* lU[2];
    #pragma unroll
    for (int j = 0; j < 2; ++j) {
        int row = wave * 16 + j * 8 + r8;
        gG[j] = Wgb + ((size_t)e * INTER + col0 + row) * HIDDEN + sgm * 8;
        gU[j] = Wub + ((size_t)e * INTER + col0 + row) * HIDDEN + sgm * 8;
        lG[j] = &sG[0][(wave * 16 + j * 8) * 64];
        lU[j] = &sU[0][(wave * 16 + j * 8) * 64];
    }

#define STAGE1(b) do {                                                        \
    _Pragma("unroll") for (int j = 0; j < 4; ++j) {                           \
        gll16(gA[j], lA[j] + (b) * (128 * 64)); gA[j] += 64; }                \
    _Pragma("unroll") for (int j = 0; j < 2; ++j) {                           \
        gll16(gG[j], lG[j] + (b) * (64 * 64));  gG[j] += 64;                  \
        gll16(gU[j], lU[j] + (b) * (64 * 64));  gU[j] += 64; }                \
} while (0)

    f32x4 accg[4][2], accu[4][2];
    #pragma unroll
    for (int i = 0; i < 4; ++i)
        #pragma unroll
        for (int j = 0; j < 2; ++j) {
            accg[i][j] = (f32x4){0.f, 0.f, 0.f, 0.f};
            accu[i][j] = (f32x4){0.f, 0.f, 0.f, 0.f};
        }

    const int wm = (wave >> 1) * 64, wn = (wave & 1) * 32;
    const int lm = lane & 15, quad = lane >> 4;
    const int x  = lane & 7;

    STAGE1(0);   // prologue

    for (int ks = 0; ks < HIDDEN / 64; ++ks) {
        __syncthreads();                       // drains DMA of buf b; frees buf b^1
        const int b = ks & 1;
        if (ks + 1 < HIDDEN / 64) STAGE1(b ^ 1);   // async; drains at NEXT barrier
        #pragma unroll
        for (int kk = 0; kk < 64; kk += 32) {
            const int ps = (((kk >> 3) + quad) ^ x) * 8;   // swizzled seg offset
            bf16x8 af[4], gf[2], uf[2];
            #pragma unroll
            for (int mi = 0; mi < 4; ++mi)
                af[mi] = *(const bf16x8*)&sA[b][(wm + mi * 16 + lm) * 64 + ps];
            #pragma unroll
            for (int ni = 0; ni < 2; ++ni) {
                gf[ni] = *(const bf16x8*)&sG[b][(wn + ni * 16 + lm) * 64 + ps];
                uf[ni] = *(const bf16x8*)&sU[b][(wn + ni * 16 + lm) * 64 + ps];
            }
            #pragma unroll
            for (int mi = 0; mi < 4; ++mi)
                #pragma unroll
                for (int ni = 0; ni < 2; ++ni) {
                    accg[mi][ni] = __builtin_amdgcn_mfma_f32_16x16x32_bf16(af[mi], gf[ni], accg[mi][ni], 0, 0, 0);
                    accu[mi][ni] = __builtin_amdgcn_mfma_f32_16x16x32_bf16(af[mi], uf[ni], accu[mi][ni], 0, 0, 0);
                }
        }
    }
#undef STAGE1

    #pragma unroll
    for (int mi = 0; mi < 4; ++mi) {
        #pragma unroll
        for (int reg = 0; reg < 4; ++reg) {
            int lr = wm + mi * 16 + quad * 4 + reg;   // C/D: col=lane&15, row=quad*4+reg
            int r  = row0 + lr;
            if (r < cnt) {
                size_t hrow = (size_t)(o0 + r) * INTER;
                #pragma unroll
                for (int ni = 0; ni < 2; ++ni) {
                    float g = accg[mi][ni][reg];
                    float u = accu[mi][ni][reg];
                    float h = g / (1.f + __expf(-g)) * u;
                    H[hrow + col0 + wn + ni * 16 + lm] = f2b(h);
                }
            }
        }
    }
}

// =================== GEMM2: down proj, weighted atomic combine ===================
// tile 128(M) x 128(N), BK=64, K=1408 (22 steps). Same pipeline structure.
__global__ __launch_bounds__(256, 2) void gemm2_k(
    const unsigned short* __restrict__ H,
    const unsigned short* __restrict__ Wdb,
    const int* __restrict__ off, const int* __restrict__ tok,
    const float* __restrict__ wgt,
    float* __restrict__ out) {

    const int e    = blockIdx.z;
    const int o0   = off[e];
    const int cnt  = off[e + 1] - o0;
    const int row0 = blockIdx.x * 128;
    if (row0 >= cnt) return;
    const int col0 = blockIdx.y * 128;

    __shared__ __align__(16) unsigned short sA[2][128 * 64];
    __shared__ __align__(16) unsigned short sB[2][128 * 64];
    __shared__ int   stok[128];
    __shared__ float swgt[128];

    const int tid = threadIdx.x;
    if (tid < 128) {
        int r  = row0 + tid;
        int rr = (r < cnt ? r : cnt - 1);
        stok[tid] = tok[o0 + rr];
        swgt[tid] = wgt[o0 + rr];
    }
    __syncthreads();

    const int wave = tid >> 6, lane = tid & 63;
    const int r8  = lane >> 3;
    const int spn = lane & 7;
    const int sgm = spn ^ r8;

    const unsigned short* gA[4]; unsigned short* lA[4];
    const unsigned short* gB[4]; unsigned short* lB[4];
    #pragma unroll
    for (int j = 0; j < 4; ++j) {
        int row = wave * 32 + j * 8 + r8;
        int gr  = row0 + row; if (gr >= cnt) gr = cnt - 1;
        gA[j] = H + (size_t)(o0 + gr) * INTER + sgm * 8;
        lA[j] = &sA[0][(wave * 32 + j * 8) * 64];
        gB[j] = Wdb + ((size_t)e * HIDDEN + col0 + row) * INTER + sgm * 8;
        lB[j] = &sB[0][(wave * 32 + j * 8) * 64];
    }

#define STAGE2(b) do {                                                        \
    _Pragma("unroll") for (int j = 0; j < 4; ++j) {                           \
        gll16(gA[j], lA[j] + (b) * (128 * 64)); gA[j] += 64;                  \
        gll16(gB[j], lB[j] + (b) * (128 * 64)); gB[j] += 64; }                \
} while (0)

    f32x4 acc[4][4];
    #pragma unroll
    for (int i = 0; i < 4; ++i)
        #pragma unroll
        for (int j = 0; j < 4; ++j) acc[i][j] = (f32x4){0.f, 0.f, 0.f, 0.f};

    const int wm = (wave >> 1) * 64, wn = (wave & 1) * 64;
    const int lm = lane & 15, quad = lane >> 4;
    const int x  = lane & 7;

    STAGE2(0);

    for (int ks = 0; ks < INTER / 64; ++ks) {
        __syncthreads();
        const int b = ks & 1;
        if (ks + 1 < INTER / 64) STAGE2(b ^ 1);
        #pragma unroll
        for (int kk = 0; kk < 64; kk += 32) {
            const int ps = (((kk >> 3) + quad) ^ x) * 8;
            bf16x8 af[4], bf[4];
            #pragma unroll
            for (int mi = 0; mi < 4; ++mi)
                af[mi] = *(const bf16x8*)&sA[b][(wm + mi * 16 + lm) * 64 + ps];
            #pragma unroll
            for (int ni = 0; ni < 4; ++ni)
                bf[ni] = *(const bf16x8*)&sB[b][(wn + ni * 16 + lm) * 64 + ps];
            #pragma unroll
            for (int mi = 0; mi < 4; ++mi)
                #pragma unroll
                for (int ni = 0; ni < 4; ++ni)
                    acc[mi][ni] = __builtin_amdgcn_mfma_f32_16x16x32_bf16(af[mi], bf[ni], acc[mi][ni], 0, 0, 0);
        }
    }
#undef STAGE2

    #pragma unroll
    for (int mi = 0; mi < 4; ++mi) {
        #pragma unroll
        for (int reg = 0; reg < 4; ++reg) {
            int lr = wm + mi * 16 + quad * 4 + reg;
            int r  = row0 + lr;
            if (r < cnt) {
                int   t = stok[lr];
                float w = swgt[lr];
                #pragma unroll
                for (int ni = 0; ni < 4; ++ni)
                    atomicAdd(&out[(size_t)t * HIDDEN + col0 + wn + ni * 16 + lm],
                              w * acc[mi][ni][reg]);
            }
        }
    }
}

extern "C" void kernel_launch(void* const* d_in, const int* in_sizes, int n_in,
                              void* d_out, int out_size, void* d_ws, size_t ws_size,
                              hipStream_t stream) {
    const float* X   = (const float*)d_in[0];
    const int*   idx = (const int*)d_in[1];
    const float* tw  = (const float*)d_in[2];
    const float* Wg  = (const float*)d_in[3];
    const float* Wu  = (const float*)d_in[4];
    const float* Wd  = (const float*)d_in[5];
    float* out = (float*)d_out;

    char* ws = (char*)d_ws;
    const size_t OFF_TOK = 64;
    const size_t OFF_WGT = 64 + (size_t)NPAIR * 4;
    const size_t OFF_XB  = 65536;
    const size_t OFF_H   = OFF_XB + (size_t)TOKENS * HIDDEN * 2;           // 8 MB Xb
    const size_t WELEMS  = (size_t)NEXP * INTER * HIDDEN;                  // 23.07M
    const size_t OFF_WG  = OFF_H + (size_t)NPAIR * INTER * 2;              // 11.5 MB H
    const size_t OFF_WU  = OFF_WG + WELEMS * 2;
    const size_t OFF_WD  = OFF_WU + WELEMS * 2;

    int*            off = (int*)ws;
    int*            tok = (int*)(ws + OFF_TOK);
    float*          wgt = (float*)(ws + OFF_WGT);
    unsigned short* Xb  = (unsigned short*)(ws + OFF_XB);
    unsigned short* H   = (unsigned short*)(ws + OFF_H);
    unsigned short* Wgb = (unsigned short*)(ws + OFF_WG);
    unsigned short* Wub = (unsigned short*)(ws + OFF_WU);
    unsigned short* Wdb = (unsigned short*)(ws + OFF_WD);

    hipMemsetAsync(d_out, 0, (size_t)out_size * sizeof(float), stream);

    route_k<<<1, 256, 0, stream>>>(idx, tw, off, tok, wgt);
    conv_k<<<(TOKENS * HIDDEN / 4 + 255) / 256, 256, 0, stream>>>(X, Xb, TOKENS * HIDDEN);

    const int wn4 = (int)(WELEMS / 4);
    conv_k<<<(wn4 + 255) / 256, 256, 0, stream>>>(Wg, Wgb, (int)WELEMS);
    conv_k<<<(wn4 + 255) / 256, 256, 0, stream>>>(Wu, Wub, (int)WELEMS);
    conv_k<<<(wn4 + 255) / 256, 256, 0, stream>>>(Wd, Wdb, (int)WELEMS);

    gemm1_k<<<dim3(NPAIR / 128, INTER / 64, NEXP), 256, 0, stream>>>(Xb, Wgb, Wub, off, tok, H);
    gemm2_k<<<dim3(NPAIR / 128, HIDDEN / 128, NEXP), 256, 0, stream>>>(H, Wdb, off, tok, wgt, out);
}

// Round 5
// 923.373 us; speedup vs baseline: 2.7552x; 1.1966x over previous
//
#include <hip/hip_runtime.h>
#include <hip/hip_bf16.h>
#include <stdint.h>

#define TOKENS 2048
#define HIDDEN 2048
#define INTER  1408
#define NEXP   8
#define NPAIR  4096

#define SK 72   // padded LDS row stride (bf16 elems)

typedef __attribute__((ext_vector_type(8))) short bf16x8;
typedef __attribute__((ext_vector_type(4))) float f32x4;

static __device__ __forceinline__ unsigned short f2b(float f) {
    union { float f; uint32_t u; } v; v.f = f;
    uint32_t r = (v.u + 0x7FFFu + ((v.u >> 16) & 1u)) >> 16;   // RNE
    return (unsigned short)r;
}

// ---------------- routing: pack (token, weight) per expert ----------------
__global__ void route_k(const int* __restrict__ idx, const float* __restrict__ w,
                        int* __restrict__ off, int* __restrict__ tok,
                        float* __restrict__ wgt) {
    __shared__ int cnt[NEXP];
    __shared__ int cur[NEXP];
    int tid = threadIdx.x;
    if (tid < NEXP) cnt[tid] = 0;
    __syncthreads();
    for (int i = tid; i < NPAIR; i += 256) atomicAdd(&cnt[idx[i]], 1);
    __syncthreads();
    if (tid == 0) {
        int s = 0;
        for (int e = 0; e < NEXP; ++e) { off[e] = s; cur[e] = s; s += cnt[e]; }
        off[NEXP] = s;
    }
    __syncthreads();
    for (int i = tid; i < NPAIR; i += 256) {
        int e = idx[i];
        int p = atomicAdd(&cur[e], 1);
        tok[p] = i >> 1;
        wgt[p] = w[i];
    }
}

// ---------------- fp32 -> bf16 bulk convert ----------------
__global__ void conv_k(const float* __restrict__ x, unsigned short* __restrict__ xb, int n) {
    int i = (blockIdx.x * blockDim.x + threadIdx.x) * 4;
    if (i < n) {
        float4 v = *(const float4*)(x + i);
        ushort4 o;
        o.x = f2b(v.x); o.y = f2b(v.y); o.z = f2b(v.z); o.w = f2b(v.w);
        *(ushort4*)(xb + i) = o;
    }
}

// =================== GEMM1: gate+up fused, SwiGLU -> H (bf16) ===================
// grid (x=expert, y=rowtile, z=coltile) -> expert maps to XCD (id%8 heuristic).
// tile 128(M) x 64(N), BK=64. Plain loads; LDS double-buffer; ONE barrier/step:
//   write(b) ; sync ; prefetch regs(k+1) ; mfma(b)
// Buffer b is not overwritten until two steps later, after an intervening sync.
__global__ __launch_bounds__(256, 2) void gemm1_k(
    const unsigned short* __restrict__ Xb,
    const unsigned short* __restrict__ Wgb, const unsigned short* __restrict__ Wub,
    const int* __restrict__ off, const int* __restrict__ tok,
    unsigned short* __restrict__ H) {

    const int e    = blockIdx.x;
    const int o0   = off[e];
    const int cnt  = off[e + 1] - o0;
    const int row0 = blockIdx.y * 128;
    if (row0 >= cnt) return;
    const int col0 = blockIdx.z * 64;

    __shared__ __align__(16) unsigned short sA[2][128 * SK];
    __shared__ __align__(16) unsigned short sG[2][64 * SK];
    __shared__ __align__(16) unsigned short sU[2][64 * SK];
    __shared__ int stok[128];

    const int tid = threadIdx.x;
    if (tid < 128) {
        int r = row0 + tid;
        stok[tid] = tok[o0 + (r < cnt ? r : cnt - 1)];
    }
    __syncthreads();

    // staging: 16B segments. A:128x8 (4/thr), G:64x8 (2/thr), U:64x8 (2/thr)
    int laddrA[4]; const unsigned short* gA[4];
    #pragma unroll
    for (int j = 0; j < 4; ++j) {
        int s = tid + 256 * j, r = s >> 3, c = (s & 7) * 8;
        laddrA[j] = r * SK + c;
        gA[j] = Xb + (size_t)stok[r] * HIDDEN + c;
    }
    int laddrB[2]; const unsigned short* gG[2]; const unsigned short* gU[2];
    #pragma unroll
    for (int j = 0; j < 2; ++j) {
        int s = tid + 256 * j, r = s >> 3, c = (s & 7) * 8;
        laddrB[j] = r * SK + c;
        gG[j] = Wgb + ((size_t)e * INTER + col0 + r) * HIDDEN + c;
        gU[j] = Wub + ((size_t)e * INTER + col0 + r) * HIDDEN + c;
    }

    const int wave = tid >> 6, lane = tid & 63;
    const int wm = (wave >> 1) * 64, wn = (wave & 1) * 32;
    const int lm = lane & 15, quad = lane >> 4;

    f32x4 accg[4][2], accu[4][2];
    #pragma unroll
    for (int i = 0; i < 4; ++i)
        #pragma unroll
        for (int j = 0; j < 2; ++j) {
            accg[i][j] = (f32x4){0.f, 0.f, 0.f, 0.f};
            accu[i][j] = (f32x4){0.f, 0.f, 0.f, 0.f};
        }

    int4 pa[4], pg[2], pu[2];
    #pragma unroll
    for (int j = 0; j < 4; ++j) pa[j] = *(const int4*)(gA[j]);
    #pragma unroll
    for (int j = 0; j < 2; ++j) { pg[j] = *(const int4*)(gG[j]); pu[j] = *(const int4*)(gU[j]); }

    const int NS = HIDDEN / 64;
    for (int ks = 0; ks < NS; ++ks) {
        const int b = ks & 1;
        #pragma unroll
        for (int j = 0; j < 4; ++j) *(int4*)&sA[b][laddrA[j]] = pa[j];
        #pragma unroll
        for (int j = 0; j < 2; ++j) {
            *(int4*)&sG[b][laddrB[j]] = pg[j];
            *(int4*)&sU[b][laddrB[j]] = pu[j];
        }
        __syncthreads();
        if (ks + 1 < NS) {          // prefetch next slice; latency overlaps MFMA below
            int k1 = (ks + 1) * 64;
            #pragma unroll
            for (int j = 0; j < 4; ++j) pa[j] = *(const int4*)(gA[j] + k1);
            #pragma unroll
            for (int j = 0; j < 2; ++j) { pg[j] = *(const int4*)(gG[j] + k1); pu[j] = *(const int4*)(gU[j] + k1); }
        }
        #pragma unroll
        for (int kk = 0; kk < 64; kk += 32) {
            bf16x8 af[4], gf[2], uf[2];
            #pragma unroll
            for (int mi = 0; mi < 4; ++mi)
                af[mi] = *(const bf16x8*)&sA[b][(wm + mi * 16 + lm) * SK + kk + quad * 8];
            #pragma unroll
            for (int ni = 0; ni < 2; ++ni) {
                gf[ni] = *(const bf16x8*)&sG[b][(wn + ni * 16 + lm) * SK + kk + quad * 8];
                uf[ni] = *(const bf16x8*)&sU[b][(wn + ni * 16 + lm) * SK + kk + quad * 8];
            }
            #pragma unroll
            for (int mi = 0; mi < 4; ++mi)
                #pragma unroll
                for (int ni = 0; ni < 2; ++ni) {
                    accg[mi][ni] = __builtin_amdgcn_mfma_f32_16x16x32_bf16(af[mi], gf[ni], accg[mi][ni], 0, 0, 0);
                    accu[mi][ni] = __builtin_amdgcn_mfma_f32_16x16x32_bf16(af[mi], uf[ni], accu[mi][ni], 0, 0, 0);
                }
        }
    }

    #pragma unroll
    for (int mi = 0; mi < 4; ++mi) {
        #pragma unroll
        for (int reg = 0; reg < 4; ++reg) {
            int lr = wm + mi * 16 + quad * 4 + reg;   // C/D: col=lane&15, row=quad*4+reg
            int r  = row0 + lr;
            if (r < cnt) {
                size_t hrow = (size_t)(o0 + r) * INTER;
                #pragma unroll
                for (int ni = 0; ni < 2; ++ni) {
                    float g = accg[mi][ni][reg];
                    float u = accu[mi][ni][reg];
                    float h = g / (1.f + __expf(-g)) * u;
                    H[hrow + col0 + wn + ni * 16 + lm] = f2b(h);
                }
            }
        }
    }
}

// =================== GEMM2: down proj, weighted atomic combine ===================
// tile 128(M) x 128(N), BK=64. Same pipeline structure.
__global__ __launch_bounds__(256, 2) void gemm2_k(
    const unsigned short* __restrict__ H,
    const unsigned short* __restrict__ Wdb,
    const int* __restrict__ off, const int* __restrict__ tok,
    const float* __restrict__ wgt,
    float* __restrict__ out) {

    const int e    = blockIdx.x;
    const int o0   = off[e];
    const int cnt  = off[e + 1] - o0;
    const int row0 = blockIdx.y * 128;
    if (row0 >= cnt) return;
    const int col0 = blockIdx.z * 128;

    __shared__ __align__(16) unsigned short sA[2][128 * SK];
    __shared__ __align__(16) unsigned short sB[2][128 * SK];
    __shared__ int   stok[128];
    __shared__ float swgt[128];

    const int tid = threadIdx.x;
    if (tid < 128) {
        int r  = row0 + tid;
        int rr = (r < cnt ? r : cnt - 1);
        stok[tid] = tok[o0 + rr];
        swgt[tid] = wgt[o0 + rr];
    }
    __syncthreads();

    int laddr[4];
    const unsigned short* gA[4]; const unsigned short* gB[4];
    #pragma unroll
    for (int j = 0; j < 4; ++j) {
        int s = tid + 256 * j, r = s >> 3, c = (s & 7) * 8;
        laddr[j] = r * SK + c;
        int gr = row0 + r; if (gr >= cnt) gr = cnt - 1;
        gA[j] = H + (size_t)(o0 + gr) * INTER + c;
        gB[j] = Wdb + ((size_t)e * HIDDEN + col0 + r) * INTER + c;
    }

    const int wave = tid >> 6, lane = tid & 63;
    const int wm = (wave >> 1) * 64, wn = (wave & 1) * 64;
    const int lm = lane & 15, quad = lane >> 4;

    f32x4 acc[4][4];
    #pragma unroll
    for (int i = 0; i < 4; ++i)
        #pragma unroll
        for (int j = 0; j < 4; ++j) acc[i][j] = (f32x4){0.f, 0.f, 0.f, 0.f};

    int4 pa[4], pb[4];
    #pragma unroll
    for (int j = 0; j < 4; ++j) { pa[j] = *(const int4*)(gA[j]); pb[j] = *(const int4*)(gB[j]); }

    const int NS = INTER / 64;
    for (int ks = 0; ks < NS; ++ks) {
        const int b = ks & 1;
        #pragma unroll
        for (int j = 0; j < 4; ++j) {
            *(int4*)&sA[b][laddr[j]] = pa[j];
            *(int4*)&sB[b][laddr[j]] = pb[j];
        }
        __syncthreads();
        if (ks + 1 < NS) {
            int k1 = (ks + 1) * 64;
            #pragma unroll
            for (int j = 0; j < 4; ++j) { pa[j] = *(const int4*)(gA[j] + k1); pb[j] = *(const int4*)(gB[j] + k1); }
        }
        #pragma unroll
        for (int kk = 0; kk < 64; kk += 32) {
            bf16x8 af[4], bf[4];
            #pragma unroll
            for (int mi = 0; mi < 4; ++mi)
                af[mi] = *(const bf16x8*)&sA[b][(wm + mi * 16 + lm) * SK + kk + quad * 8];
            #pragma unroll
            for (int ni = 0; ni < 4; ++ni)
                bf[ni] = *(const bf16x8*)&sB[b][(wn + ni * 16 + lm) * SK + kk + quad * 8];
            #pragma unroll
            for (int mi = 0; mi < 4; ++mi)
                #pragma unroll
                for (int ni = 0; ni < 4; ++ni)
                    acc[mi][ni] = __builtin_amdgcn_mfma_f32_16x16x32_bf16(af[mi], bf[ni], acc[mi][ni], 0, 0, 0);
        }
    }

    #pragma unroll
    for (int mi = 0; mi < 4; ++mi) {
        #pragma unroll
        for (int reg = 0; reg < 4; ++reg) {
            int lr = wm + mi * 16 + quad * 4 + reg;
            int r  = row0 + lr;
            if (r < cnt) {
                int   t = stok[lr];
                float w = swgt[lr];
                #pragma unroll
                for (int ni = 0; ni < 4; ++ni)
                    atomicAdd(&out[(size_t)t * HIDDEN + col0 + wn + ni * 16 + lm],
                              w * acc[mi][ni][reg]);
            }
        }
    }
}

extern "C" void kernel_launch(void* const* d_in, const int* in_sizes, int n_in,
                              void* d_out, int out_size, void* d_ws, size_t ws_size,
                              hipStream_t stream) {
    const float* X   = (const float*)d_in[0];
    const int*   idx = (const int*)d_in[1];
    const float* tw  = (const float*)d_in[2];
    const float* Wg  = (const float*)d_in[3];
    const float* Wu  = (const float*)d_in[4];
    const float* Wd  = (const float*)d_in[5];
    float* out = (float*)d_out;

    char* ws = (char*)d_ws;
    const size_t OFF_TOK = 64;
    const size_t OFF_WGT = 64 + (size_t)NPAIR * 4;
    const size_t OFF_XB  = 65536;
    const size_t OFF_H   = OFF_XB + (size_t)TOKENS * HIDDEN * 2;           // 8 MB Xb
    const size_t WELEMS  = (size_t)NEXP * INTER * HIDDEN;                  // 23.07M
    const size_t OFF_WG  = OFF_H + (size_t)NPAIR * INTER * 2;              // 11.5 MB H
    const size_t OFF_WU  = OFF_WG + WELEMS * 2;
    const size_t OFF_WD  = OFF_WU + WELEMS * 2;

    int*            off = (int*)ws;
    int*            tok = (int*)(ws + OFF_TOK);
    float*          wgt = (float*)(ws + OFF_WGT);
    unsigned short* Xb  = (unsigned short*)(ws + OFF_XB);
    unsigned short* H   = (unsigned short*)(ws + OFF_H);
    unsigned short* Wgb = (unsigned short*)(ws + OFF_WG);
    unsigned short* Wub = (unsigned short*)(ws + OFF_WU);
    unsigned short* Wdb = (unsigned short*)(ws + OFF_WD);

    hipMemsetAsync(d_out, 0, (size_t)out_size * sizeof(float), stream);

    route_k<<<1, 256, 0, stream>>>(idx, tw, off, tok, wgt);
    conv_k<<<(TOKENS * HIDDEN / 4 + 255) / 256, 256, 0, stream>>>(X, Xb, TOKENS * HIDDEN);

    const int wn4 = (int)(WELEMS / 4);
    conv_k<<<(wn4 + 255) / 256, 256, 0, stream>>>(Wg, Wgb, (int)WELEMS);
    conv_k<<<(wn4 + 255) / 256, 256, 0, stream>>>(Wu, Wub, (int)WELEMS);
    conv_k<<<(wn4 + 255) / 256, 256, 0, stream>>>(Wd, Wdb, (int)WELEMS);

    // x = expert: consecutive block IDs spread experts across XCDs (id%8),
    // giving each XCD one expert's X/W stream (~2.5 MB, fits 4 MB L2).
    gemm1_k<<<dim3(NEXP, NPAIR / 128, INTER / 64), 256, 0, stream>>>(Xb, Wgb, Wub, off, tok, H);
    gemm2_k<<<dim3(NEXP, NPAIR / 128, HIDDEN / 128), 256, 0, stream>>>(H, Wdb, off, tok, wgt, out);
}